// Round 1
// 1123.762 us; speedup vs baseline: 1.5656x; 1.5656x over previous
//
#include <hip/hip_runtime.h>

// TreeLstmDecoder: B=64 trees, K=4, D=6, V=600, L=256, N_PER=1365, N=87360.
// Restructured for minimum launch count (~40 dispatches):
//  - ONE pack kernel (all weight conversions / concats / transposes).
//  - ONE batched s=0 sibling LSTM for all depths (no chain dependence).
//  - Per depth: ONE fused hoist GEMM (Hpar@[Up;Whhp]) with split epilogue
//    (PP raw + tanh->HPRED_ALL s=0 rows + parent gates), ONE batched parent
//    LSTM over all 4 sibling groups, and per sibling step s>=1 ONE fused
//    GEMM (HS@[Us;Whhs]) producing HPRED_ALL rows + sibling gates.
//  - ONE final logits GEMM (87360x602x256) + ONE softmax over all nodes
//    (w_off terms cancel inside log_softmax).
// All GEMMs: C = A*B^T, K=256, bf16 operands, fp32 accumulate via MFMA.

typedef unsigned short u16;
typedef short bf16x8 __attribute__((ext_vector_type(8)));
typedef float f32x4 __attribute__((ext_vector_type(4)));

#define NPER 1365
#define VDIM 600
#define VD2  602

__device__ __forceinline__ float b2f(u16 h) {
  union { unsigned u; float f; } v; v.u = ((unsigned)h) << 16; return v.f;
}
__device__ __forceinline__ u16 f2bf(float f) {
  union { float f; unsigned u; } v; v.f = f;
  unsigned r = v.u + 0x7fff + ((v.u >> 16) & 1);
  return (u16)(r >> 16);
}
__device__ __forceinline__ float sigm(float x) { return 1.f / (1.f + expf(-x)); }

// ---------------- single pack kernel (ws is re-poisoned every call) ---------
// Segments: UPWHHP[1280,256], USWHHS[1280,256], ZBF[64,256],
//           WIHPT[600,1024], WIHST[600,1024], WEXT[602,256], BE[602],
//           BP[1024], BS[1024].
__global__ void k_pack(
    const float* __restrict__ Upar, const float* __restrict__ Whhp,
    const float* __restrict__ Usib, const float* __restrict__ Whhs,
    const float* __restrict__ z, const float* __restrict__ Wihp,
    const float* __restrict__ Wihs, const float* __restrict__ Wlab,
    const float* __restrict__ Wd, const float* __restrict__ Ww,
    const float* __restrict__ blab, const float* __restrict__ bd,
    const float* __restrict__ bw, const float* __restrict__ bihp,
    const float* __restrict__ bhhp, const float* __restrict__ bihs,
    const float* __restrict__ bhhs,
    u16* __restrict__ UPWHHP, u16* __restrict__ USWHHS, u16* __restrict__ ZBF,
    u16* __restrict__ WIHPT, u16* __restrict__ WIHST, u16* __restrict__ WEXT,
    float* __restrict__ BE, float* __restrict__ BP, float* __restrict__ BS) {
  int i = blockIdx.x * 256 + threadIdx.x;
  if (i < 327680) {
    int r = i >> 8, c = i & 255;
    UPWHHP[i] = f2bf(r < 256 ? Upar[(r << 8) | c] : Whhp[((r - 256) << 8) | c]);
    return;
  }
  i -= 327680;
  if (i < 327680) {
    int r = i >> 8, c = i & 255;
    USWHHS[i] = f2bf(r < 256 ? Usib[(r << 8) | c] : Whhs[((r - 256) << 8) | c]);
    return;
  }
  i -= 327680;
  if (i < 16384) { ZBF[i] = f2bf(z[i]); return; }
  i -= 16384;
  if (i < 614400) {  // W_ih_p [1024,600] -> [600,1024]
    int r = i / VDIM, c = i - r * VDIM;
    WIHPT[c * 1024 + r] = f2bf(Wihp[i]); return;
  }
  i -= 614400;
  if (i < 614400) {
    int r = i / VDIM, c = i - r * VDIM;
    WIHST[c * 1024 + r] = f2bf(Wihs[i]); return;
  }
  i -= 614400;
  if (i < VD2 * 256) {
    int r = i >> 8, c = i & 255;
    float v = (r < VDIM) ? Wlab[r * 256 + c] : ((r == VDIM) ? Wd[c] : Ww[c]);
    WEXT[i] = f2bf(v); return;
  }
  i -= VD2 * 256;
  if (i < VD2) { BE[i] = (i < VDIM) ? blab[i] : ((i == VDIM) ? bd[0] : bw[0]); return; }
  i -= VD2;
  if (i < 1024) { BP[i] = bihp[i] + bhhp[i]; return; }
  i -= 1024;
  if (i < 1024) { BS[i] = bihs[i] + bhhs[i]; return; }
}

// ---------------- fused dual GEMM: C = A*B^T, B=[1280,256] concat -----------
// Blocks with n0<256:  v = acc (+PPadd); optional rawPP store; always
//                      tanh(v) -> HPRED_ALL at node rows t*NPER+sps+4j.
// Blocks with n0>=256: gates[row,col-256] = acc (raw, bf16).
__global__ __launch_bounds__(256) void k_mm_dual(
    const u16* __restrict__ A, const u16* __restrict__ B,
    const u16* __restrict__ PPadd, u16* __restrict__ rawPP,
    u16* __restrict__ gates, u16* __restrict__ node_out,
    int M, int pcs, int sps) {
  __shared__ __align__(16) u16 As[128 * 40];
  __shared__ __align__(16) u16 Bs[128 * 40];
  const int m0 = blockIdx.x * 128, n0 = blockIdx.y * 128;
  const int tid = threadIdx.x;
  const int wave = tid >> 6, lane = tid & 63;
  const int quad = lane >> 4, lr = lane & 15;
  const int wm = (wave >> 1) * 64, wn = (wave & 1) * 64;
  const int srow = tid >> 2;
  const int sch = (tid & 3) << 3;

  f32x4 acc[4][4] = {};
  for (int t = 0; t < 8; ++t) {
    const int kk = t * 32;
    bf16x8 a0 = *(const bf16x8*)(A + (size_t)(m0 + srow) * 256 + kk + sch);
    bf16x8 a1 = *(const bf16x8*)(A + (size_t)(m0 + srow + 64) * 256 + kk + sch);
    bf16x8 b0 = *(const bf16x8*)(B + (size_t)(n0 + srow) * 256 + kk + sch);
    bf16x8 b1 = *(const bf16x8*)(B + (size_t)(n0 + srow + 64) * 256 + kk + sch);
    __syncthreads();
    *(bf16x8*)&As[srow * 40 + sch] = a0;
    *(bf16x8*)&As[(srow + 64) * 40 + sch] = a1;
    *(bf16x8*)&Bs[srow * 40 + sch] = b0;
    *(bf16x8*)&Bs[(srow + 64) * 40 + sch] = b1;
    __syncthreads();
    bf16x8 af[4], bfr[4];
#pragma unroll
    for (int tm = 0; tm < 4; ++tm)
      af[tm] = *(const bf16x8*)&As[(wm + tm * 16 + lr) * 40 + quad * 8];
#pragma unroll
    for (int tn = 0; tn < 4; ++tn)
      bfr[tn] = *(const bf16x8*)&Bs[(wn + tn * 16 + lr) * 40 + quad * 8];
#pragma unroll
    for (int tm = 0; tm < 4; ++tm)
#pragma unroll
      for (int tn = 0; tn < 4; ++tn)
        acc[tm][tn] = __builtin_amdgcn_mfma_f32_16x16x32_bf16(
            af[tm], bfr[tn], acc[tm][tn], 0, 0, 0);
  }

  const bool isg = (n0 >= 256);
#pragma unroll
  for (int tn = 0; tn < 4; ++tn) {
    int col = n0 + wn + tn * 16 + lr;
#pragma unroll
    for (int tm = 0; tm < 4; ++tm) {
#pragma unroll
      for (int r = 0; r < 4; ++r) {
        int row = m0 + wm + tm * 16 + quad * 4 + r;
        if (row >= M) continue;
        float v = acc[tm][tn][r];
        if (isg) {
          gates[(size_t)row * 1024 + (col - 256)] = f2bf(v);
        } else {
          if (PPadd) v += b2f(PPadd[(size_t)row * 256 + col]);
          if (rawPP) rawPP[(size_t)row * 256 + col] = f2bf(v);
          int tt = row >> pcs, j = row & ((1 << pcs) - 1);
          node_out[(size_t)(tt * NPER + sps + 4 * j) * 256 + col] = f2bf(tanhf(v));
        }
      }
    }
  }
}

// ---------------- final logits GEMM: fp32 out + bias ------------------------
__global__ __launch_bounds__(256) void k_mm_logits(
    const u16* __restrict__ A, const u16* __restrict__ B,
    const float* __restrict__ bias, float* __restrict__ C, int M, int N) {
  __shared__ __align__(16) u16 As[128 * 40];
  __shared__ __align__(16) u16 Bs[128 * 40];
  const int m0 = blockIdx.x * 128, n0 = blockIdx.y * 128;
  const int tid = threadIdx.x;
  const int wave = tid >> 6, lane = tid & 63;
  const int quad = lane >> 4, lr = lane & 15;
  const int wm = (wave >> 1) * 64, wn = (wave & 1) * 64;
  const int srow = tid >> 2;
  const int sch = (tid & 3) << 3;

  f32x4 acc[4][4] = {};
  for (int t = 0; t < 8; ++t) {
    const int kk = t * 32;
    bf16x8 a0 = *(const bf16x8*)(A + (size_t)(m0 + srow) * 256 + kk + sch);
    bf16x8 a1 = *(const bf16x8*)(A + (size_t)(m0 + srow + 64) * 256 + kk + sch);
    bf16x8 b0 = *(const bf16x8*)(B + (size_t)(n0 + srow) * 256 + kk + sch);
    bf16x8 b1 = *(const bf16x8*)(B + (size_t)(n0 + srow + 64) * 256 + kk + sch);
    __syncthreads();
    *(bf16x8*)&As[srow * 40 + sch] = a0;
    *(bf16x8*)&As[(srow + 64) * 40 + sch] = a1;
    *(bf16x8*)&Bs[srow * 40 + sch] = b0;
    *(bf16x8*)&Bs[(srow + 64) * 40 + sch] = b1;
    __syncthreads();
    bf16x8 af[4], bfr[4];
#pragma unroll
    for (int tm = 0; tm < 4; ++tm)
      af[tm] = *(const bf16x8*)&As[(wm + tm * 16 + lr) * 40 + quad * 8];
#pragma unroll
    for (int tn = 0; tn < 4; ++tn)
      bfr[tn] = *(const bf16x8*)&Bs[(wn + tn * 16 + lr) * 40 + quad * 8];
#pragma unroll
    for (int tm = 0; tm < 4; ++tm)
#pragma unroll
      for (int tn = 0; tn < 4; ++tn)
        acc[tm][tn] = __builtin_amdgcn_mfma_f32_16x16x32_bf16(
            af[tm], bfr[tn], acc[tm][tn], 0, 0, 0);
  }

#pragma unroll
  for (int tn = 0; tn < 4; ++tn) {
    int col = n0 + wn + tn * 16 + lr;
    if (col >= N) continue;
    float bv = bias[col];
#pragma unroll
    for (int tm = 0; tm < 4; ++tm) {
#pragma unroll
      for (int r = 0; r < 4; ++r) {
        int row = m0 + wm + tm * 16 + quad * 4 + r;
        if (row >= M) continue;
        C[(size_t)row * N + col] = acc[tm][tn][r] + bv;
      }
    }
  }
}

// ---------------- batched log_softmax over all N nodes ----------------------
__global__ __launch_bounds__(256) void k_softmax_all(
    const float* __restrict__ logits, float* __restrict__ out) {
  __shared__ float sred[8];
  __shared__ float sbc;
  int g = blockIdx.x, u = threadIdx.x;
  const float* row = logits + (size_t)g * VD2;
  float* orow = out + (size_t)g * VD2;

  float x0 = row[u];
  float x1 = row[256 + u];
  float x2 = (u < 88) ? row[512 + u] : -1e30f;
  float m = fmaxf(fmaxf(x0, x1), x2);
#pragma unroll
  for (int o = 32; o > 0; o >>= 1) m = fmaxf(m, __shfl_down(m, o, 64));
  if ((u & 63) == 0) sred[u >> 6] = m;
  __syncthreads();
  if (u == 0) sbc = fmaxf(fmaxf(sred[0], sred[1]), fmaxf(sred[2], sred[3]));
  __syncthreads();
  m = sbc;
  float e = expf(x0 - m) + expf(x1 - m) + ((u < 88) ? expf(x2 - m) : 0.f);
#pragma unroll
  for (int o = 32; o > 0; o >>= 1) e += __shfl_down(e, o, 64);
  if ((u & 63) == 0) sred[4 + (u >> 6)] = e;
  __syncthreads();
  if (u == 0) sbc = m + logf(sred[4] + sred[5] + sred[6] + sred[7]);
  __syncthreads();
  float logZ = sbc;
  orow[u] = x0 - logZ;
  orow[256 + u] = x1 - logZ;
  if (u < 88) orow[512 + u] = x2 - logZ;
  if (u == 0) orow[600] = sigm(row[600]);
  if (u == 1) orow[601] = sigm(row[601]);
}

// ---------------- LSTM elementwise ------------------------------------------

// Sibling LSTM, compact rows (g = t*Gper + j); gates/c_in may be null (s=0).
__global__ __launch_bounds__(256) void k_lstm_sib(
    const u16* __restrict__ gates, const u16* __restrict__ wihT,
    const float* __restrict__ bias, const u16* __restrict__ c_in,
    const int* __restrict__ feat, u16* __restrict__ h_out, u16* __restrict__ c_out,
    int pcs, int sps) {
  int g = blockIdx.x, u = threadIdx.x;
  int t = g >> pcs, j = g & ((1 << pcs) - 1);
  int idx = t * NPER + sps + 4 * j;
  int lab = feat[idx];
  const u16* wr = wihT + lab * 1024;
  float gi = b2f(wr[u])       + bias[u];
  float gf = b2f(wr[256 + u]) + bias[256 + u];
  float gg = b2f(wr[512 + u]) + bias[512 + u];
  float go = b2f(wr[768 + u]) + bias[768 + u];
  if (gates) {
    const u16* gr = gates + (size_t)g * 1024;
    gi += b2f(gr[u]); gf += b2f(gr[256 + u]);
    gg += b2f(gr[512 + u]); go += b2f(gr[768 + u]);
  }
  float c = c_in ? b2f(c_in[(size_t)g * 256 + u]) : 0.f;
  float cn = sigm(gf) * c + sigm(gi) * tanhf(gg);
  float hn = sigm(go) * tanhf(cn);
  h_out[(size_t)g * 256 + u] = f2bf(hn);
  c_out[(size_t)g * 256 + u] = f2bf(cn);
}

// Parent LSTM batched over all nodes at depth d (4 sibling groups at once).
// g = t*LS + p, parent row pr = t*(LS/4) + p/4 in GATESP / c_in.
__global__ __launch_bounds__(256) void k_lstm_par(
    const u16* __restrict__ gates, const u16* __restrict__ wihT,
    const float* __restrict__ bias, const u16* __restrict__ c_in,
    const int* __restrict__ feat, u16* __restrict__ h_out, u16* __restrict__ c_out,
    int lsbits, int start) {
  int g = blockIdx.x, u = threadIdx.x;
  int t = g >> lsbits, p = g & ((1 << lsbits) - 1);
  int pr = lsbits ? ((t << (lsbits - 2)) | (p >> 2)) : g;
  int idx = t * NPER + start + p;
  int lab = feat[idx];
  const u16* wr = wihT + lab * 1024;
  const u16* gr = gates + (size_t)pr * 1024;
  float gi = b2f(wr[u])       + bias[u]       + b2f(gr[u]);
  float gf = b2f(wr[256 + u]) + bias[256 + u] + b2f(gr[256 + u]);
  float gg = b2f(wr[512 + u]) + bias[512 + u] + b2f(gr[512 + u]);
  float go = b2f(wr[768 + u]) + bias[768 + u] + b2f(gr[768 + u]);
  float c = c_in ? b2f(c_in[(size_t)pr * 256 + u]) : 0.f;
  float cn = sigm(gf) * c + sigm(gi) * tanhf(gg);
  float hn = sigm(go) * tanhf(cn);
  h_out[(size_t)g * 256 + u] = f2bf(hn);
  c_out[(size_t)g * 256 + u] = f2bf(cn);
}

// s=0 sibling LSTM for ALL depths in one launch (h_prev=c_prev=0, no gates).
__global__ __launch_bounds__(256) void k_lstm_s0(
    const u16* __restrict__ wihT, const float* __restrict__ bias,
    const int* __restrict__ feat, u16* __restrict__ h_all, u16* __restrict__ c_all) {
  int g = blockIdx.x, u = threadIdx.x;
  int off, pcs, start;
  if (g < 64)        { off = 0;    pcs = 0; start = 1;   }
  else if (g < 320)  { off = 64;   pcs = 2; start = 5;   }
  else if (g < 1344) { off = 320;  pcs = 4; start = 21;  }
  else if (g < 5440) { off = 1344; pcs = 6; start = 85;  }
  else               { off = 5440; pcs = 8; start = 341; }
  int lg = g - off;
  int t = lg >> pcs, j = lg & ((1 << pcs) - 1);
  int idx = t * NPER + start + 4 * j;
  int lab = feat[idx];
  const u16* wr = wihT + lab * 1024;
  float gi = b2f(wr[u])       + bias[u];
  float gg = b2f(wr[512 + u]) + bias[512 + u];
  float go = b2f(wr[768 + u]) + bias[768 + u];
  float cn = sigm(gi) * tanhf(gg);
  float hn = sigm(go) * tanhf(cn);
  h_all[(size_t)g * 256 + u] = f2bf(hn);
  c_all[(size_t)g * 256 + u] = f2bf(cn);
}

// ---------------- host ------------------------------------------------------

extern "C" void kernel_launch(void* const* d_in, const int* in_sizes, int n_in,
                              void* d_out, int out_size, void* d_ws, size_t ws_size,
                              hipStream_t stream) {
  const float* z    = (const float*)d_in[0];
  const int*   feat = (const int*)d_in[1];
  const float* Wihp = (const float*)d_in[2];
  const float* Whhp = (const float*)d_in[3];
  const float* bihp = (const float*)d_in[4];
  const float* bhhp = (const float*)d_in[5];
  const float* Wihs = (const float*)d_in[6];
  const float* Whhs = (const float*)d_in[7];
  const float* bihs = (const float*)d_in[8];
  const float* bhhs = (const float*)d_in[9];
  const float* Upar = (const float*)d_in[10];
  const float* Usib = (const float*)d_in[11];
  const float* Wlab = (const float*)d_in[12];
  const float* blab = (const float*)d_in[13];
  const float* Wd   = (const float*)d_in[14];
  const float* bd   = (const float*)d_in[15];
  const float* Ww   = (const float*)d_in[16];
  const float* bw   = (const float*)d_in[17];
  float* out = (float*)d_out;

  char* w = (char*)d_ws;
  auto alloc = [&](size_t bytes) {
    char* p = w; w += (bytes + 255) & ~(size_t)255; return p;
  };
  u16*   UPWHHP = (u16*)alloc((size_t)1280 * 256 * 2);
  u16*   USWHHS = (u16*)alloc((size_t)1280 * 256 * 2);
  u16*   ZBF    = (u16*)alloc((size_t)128 * 256 * 2);   // rows 64..127: pad
  u16*   WIHPT  = (u16*)alloc((size_t)VDIM * 1024 * 2);
  u16*   WIHST  = (u16*)alloc((size_t)VDIM * 1024 * 2);
  u16*   WEXT   = (u16*)alloc((size_t)640 * 256 * 2);   // rows 602..639: pad
  float* BE     = (float*)alloc(VD2 * 4);
  float* BP     = (float*)alloc(1024 * 4);
  float* BS     = (float*)alloc(1024 * 4);
  const size_t SB = (size_t)16384 * 256 * 2;
  u16* HP[2] = {(u16*)alloc(SB), (u16*)alloc(SB)};
  u16* CP[2] = {(u16*)alloc(SB), (u16*)alloc(SB)};
  u16* HS[2] = {(u16*)alloc(SB), (u16*)alloc(SB)};
  u16* CS[2] = {(u16*)alloc(SB), (u16*)alloc(SB)};
  u16* HS0A  = (u16*)alloc((size_t)21824 * 256 * 2);
  u16* CS0A  = (u16*)alloc((size_t)21824 * 256 * 2);
  u16* PP    = (u16*)alloc(SB);
  u16* GATES = (u16*)alloc((size_t)16384 * 1024 * 2);
  u16* GATESP= (u16*)alloc((size_t)4096 * 1024 * 2);
  u16* HPRED = (u16*)alloc((size_t)87424 * 256 * 2);    // node-ordered, +pad
  float* LOGITS = (float*)alloc((size_t)87360 * VD2 * 4);

  // ---- one pack kernel (2,057,306 elements)
  k_pack<<<8037, 256, 0, stream>>>(Upar, Whhp, Usib, Whhs, z, Wihp, Wihs,
                                   Wlab, Wd, Ww, blab, bd, bw, bihp, bhhp,
                                   bihs, bhhs, UPWHHP, USWHHS, ZBF, WIHPT,
                                   WIHST, WEXT, BE, BP, BS);
  // ---- all s=0 sibling LSTMs (chain-independent), 21824 nodes
  k_lstm_s0<<<21824, 256, 0, stream>>>(WIHST, BS, feat, HS0A, CS0A);

  const int starts[6] = {0, 1, 5, 21, 85, 341};
  const int s0off[6]  = {0, 0, 64, 320, 1344, 5440};

  // ---- d = 0: hpred=tanh(z@Up^T)->HPRED rows t*NPER; gates=z@Whhp^T
  k_mm_dual<<<dim3(1, 10), 256, 0, stream>>>(ZBF, UPWHHP, nullptr, nullptr,
                                             GATESP, HPRED, 64, 0, 0);
  k_lstm_par<<<64, 256, 0, stream>>>(GATESP, WIHPT, BP, nullptr, feat,
                                     HP[0], CP[0], 0, 0);
  int hp = 0;

  // ---- d = 1 .. 5
  for (int d = 1; d < 6; ++d) {
    const int G = 64 << (2 * (d - 1));
    const int pcs = 2 * (d - 1);
    const int st = starts[d];
    const int gx = (G + 127) / 128;
    // hoist: PP + tanh->HPRED (s=0 rows) + parent gates (skipped at leaves)
    k_mm_dual<<<dim3(gx, d < 5 ? 10 : 2), 256, 0, stream>>>(
        HP[hp], UPWHHP, nullptr, PP, d < 5 ? GATESP : nullptr, HPRED, G, pcs, st);
    if (d < 5)
      k_lstm_par<<<64 << (2 * d), 256, 0, stream>>>(
          GATESP, WIHPT, BP, CP[hp], feat, HP[1 - hp], CP[1 - hp], 2 * d, st);
    // sibling chain (s=0 state precomputed in HS0A/CS0A)
    const u16* hsP = HS0A + (size_t)s0off[d] * 256;
    const u16* csP = CS0A + (size_t)s0off[d] * 256;
    for (int s = 1; s < 4; ++s) {
      k_mm_dual<<<dim3(gx, s < 3 ? 10 : 2), 256, 0, stream>>>(
          hsP, USWHHS, PP, nullptr, s < 3 ? GATES : nullptr, HPRED, G, pcs, st + s);
      if (s < 3) {
        u16* hd = HS[s & 1];
        u16* cd = CS[s & 1];
        k_lstm_sib<<<G, 256, 0, stream>>>(GATES, WIHST, BS, csP, feat,
                                          hd, cd, pcs, st + s);
        hsP = hd; csP = cd;
      }
    }
    if (d < 5) hp = 1 - hp;
  }

  // ---- batched tail: one logits GEMM + one softmax over all nodes
  k_mm_logits<<<dim3(683, 5), 256, 0, stream>>>(HPRED, WEXT, BE, LOGITS,
                                                87360, VD2);
  k_softmax_all<<<87360, 256, 0, stream>>>(LOGITS, out);

  (void)in_sizes; (void)n_in; (void)out_size; (void)ws_size;
}